// Round 3
// baseline (188.461 us; speedup 1.0000x reference)
//
#include <hip/hip_runtime.h>
#include <math.h>

#define B_N 131072
#define R_N 10
#define FIN_N 20

// ---------------- workspace layout (float offsets) ----------------
#define WS_STAT1 0
#define ST1_SZ   (64 * 352)          // 22528
#define WS_MT    22528               // Mt[64][20]
#define WS_C     23808               // C[20]
#define WS_STAT2 23840               // 64 stripes x 40 -> ends 26400
#define WS_NH    26400               // nhu[200], nhl[200] -> ends 26800
#define WS_ACT   26816               // act[B][64] (mode 2)
#define WS_Z2    26816               // z col-major (mode 1, no act)
#define WS_ZFULL (26816 + (size_t)64 * B_N)   // z col-major (mode 2)

// ---------------- pass 1: act (+store) + act moments ----------------
// thread -> (row-slot rl = tid>>3, group g = tid&7); grid 1024, 16 row-iters? (B/(1024*32)=4)
__global__ __launch_bounds__(256) void k_act_moments(
    const float* __restrict__ x, const float* __restrict__ cen,
    const float* __restrict__ lw, const float* __restrict__ rw,
    const float* __restrict__ linw, float* __restrict__ act_out,
    float* __restrict__ stat1, int store)
{
    __shared__ float sAcc[4][8][44];

    const int t = threadIdx.x;
    const int g = t & 7;
    const int rl = t >> 3;

    float c_[8], nh_[8], w_[8];
#pragma unroll
    for (int k = 0; k < 8; ++k) {
        c_[k] = cen[g * 8 + k];
        float s = expf(lw[g * 8 + k]) + 1e-6f;
        nh_[k] = -0.5f / (s * s);
        w_[k] = rw[g * 8 + k];
    }
    const float lin = linw[g];

    float sumA[8], P[36];
#pragma unroll
    for (int f = 0; f < 8; ++f) sumA[f] = 0.0f;
#pragma unroll
    for (int i = 0; i < 36; ++i) P[i] = 0.0f;

    for (int row = blockIdx.x * 32 + rl; row < B_N; row += gridDim.x * 32) {
        const float* xr = x + (size_t)row * 64 + g * 8;
        float4 v0 = *(const float4*)(xr);
        float4 v1 = *(const float4*)(xr + 4);
        float xv[8] = {v0.x, v0.y, v0.z, v0.w, v1.x, v1.y, v1.z, v1.w};
        float act[8];
#pragma unroll
        for (int f = 0; f < 8; ++f) {
            float v = xv[f];
            float a = lin * v;
#pragma unroll
            for (int k = 0; k < 8; ++k) {
                float d = v - c_[k];
                a += w_[k] * __expf(d * d * nh_[k]);
            }
            act[f] = a;
        }
        if (store) {
            float* ar = act_out + (size_t)row * 64 + g * 8;
            *(float4*)(ar)     = make_float4(act[0], act[1], act[2], act[3]);
            *(float4*)(ar + 4) = make_float4(act[4], act[5], act[6], act[7]);
        }
        int idx = 0;
#pragma unroll
        for (int f = 0; f < 8; ++f) {
            sumA[f] += act[f];
#pragma unroll
            for (int f2 = 0; f2 <= f; ++f2) { P[idx] += act[f] * act[f2]; ++idx; }
        }
    }

#pragma unroll
    for (int off = 32; off >= 8; off >>= 1) {
#pragma unroll
        for (int f = 0; f < 8; ++f) sumA[f] += __shfl_down(sumA[f], off, 64);
#pragma unroll
        for (int i = 0; i < 36; ++i) P[i] += __shfl_down(P[i], off, 64);
    }
    const int wave = t >> 6, lane = t & 63;
    if (lane < 8) {   // lane == g
        float* dst = &sAcc[wave][lane][0];
#pragma unroll
        for (int f = 0; f < 8; ++f) dst[f] = sumA[f];
#pragma unroll
        for (int i = 0; i < 36; ++i) dst[8 + i] = P[i];
    }
    __syncthreads();
    for (int i = t; i < 352; i += 256) {
        int gg = i / 44, v = i % 44;
        float s = sAcc[0][gg][v] + sAcc[1][gg][v] + sAcc[2][gg][v] + sAcc[3][gg][v];
        atomicAdd(&stat1[(blockIdx.x & 63) * 352 + i], s);
    }
}

// ---------------- build: BN1 from moments, fold M/C, fuzzy tables ----------------
__global__ __launch_bounds__(256) void k_build(
    const float* __restrict__ stat1, const float* __restrict__ fpW,
    const float* __restrict__ fpb, const float* __restrict__ g1,
    const float* __restrict__ b1, const float* __restrict__ Wp,
    const float* __restrict__ pb, const float* __restrict__ lsu,
    const float* __restrict__ lsl,
    float* __restrict__ Mt, float* __restrict__ Cc, float* __restrict__ nh,
    float* __restrict__ stat2)
{
    __shared__ float Am[8][8];     // E[act]
    __shared__ float Sg[8][36];    // E[act act^T] upper-tri
    __shared__ float a_[128], bb_[128];
    const int t = threadIdx.x;

    for (int i = t; i < 352; i += 256) {
        float s = 0.0f;
        for (int st = 0; st < 64; ++st) s += stat1[st * 352 + i];
        float m = s * (1.0f / B_N);
        int g = i / 44, v = i % 44;
        if (v < 8) Am[g][v] = m; else Sg[g][v - 8] = m;
    }
    __syncthreads();

    if (t < 128) {
        const int g = t >> 4;
        float wv[8];
#pragma unroll
        for (int f = 0; f < 8; ++f) wv[f] = Wp[t * 8 + f];
        float dot = 0.0f;
#pragma unroll
        for (int f = 0; f < 8; ++f) dot += wv[f] * Am[g][f];
        const float pbv = pb[t];
        const float mu = pbv + dot;
        float e2 = pbv * pbv + 2.0f * pbv * dot;
        int idx = 0;
#pragma unroll
        for (int f = 0; f < 8; ++f)
#pragma unroll
            for (int f2 = 0; f2 <= f; ++f2) {
                float c2 = (f2 == f) ? 1.0f : 2.0f;
                e2 += c2 * wv[f] * wv[f2] * Sg[g][idx]; ++idx;
            }
        const float var = e2 - mu * mu;
        const float a = g1[t] * rsqrtf(var + 1e-5f);
        a_[t] = a;
        bb_[t] = b1[t] - mu * a;
    }
    __syncthreads();

    for (int i = t; i < 1280; i += 256) {
        int gf = i / 20, j = i % 20;
        int g = gf >> 3, f = gf & 7;
        float m = 0.0f;
        for (int o = 0; o < 16; ++o) {
            int c = g * 16 + o;
            m += fpW[j * 128 + c] * a_[c] * Wp[c * 8 + f];
        }
        Mt[i] = m;
    }
    if (t < 20) {
        float cj = fpb[t];
        for (int c = 0; c < 128; ++c)
            cj += fpW[t * 128 + c] * (a_[c] * pb[c] + bb_[c]);
        Cc[t] = cj;
    }
    for (int i = t; i < 200; i += 256) {
        float su = expf(lsu[i]) + 1e-6f;
        float sl = fminf(expf(lsl[i]) + 1e-6f, 0.9f * su);
        nh[i] = -0.5f / (su * su);
        nh[200 + i] = -0.5f / (sl * sl);
    }
    for (int i = t; i < 2560; i += 256) stat2[i] = 0.0f;
}

// ---------------- pass 2 (mode 2): z = act·Mt + C, 4 rows/thread ----------------
__global__ __launch_bounds__(128) void k_z_from_act(
    const float* __restrict__ act, const float* __restrict__ Mt,
    const float* __restrict__ Cc, float* __restrict__ zout,
    float* __restrict__ stat2)
{
    __shared__ __align__(16) float sMt[1280];
    __shared__ float sC[20];
    __shared__ float sRed[2][40];

    const int t = threadIdx.x;
    for (int i = t; i < 1280; i += 128) sMt[i] = Mt[i];
    if (t < 20) sC[t] = Cc[t];
    __syncthreads();

    const int r0 = (blockIdx.x * 128 + t) * 4;
    float zp[4][20];
#pragma unroll
    for (int r = 0; r < 4; ++r)
#pragma unroll
        for (int j = 0; j < 20; ++j) zp[r][j] = sC[j];

#pragma unroll 1
    for (int g = 0; g < 8; ++g) {
        float a[4][8];
#pragma unroll
        for (int r = 0; r < 4; ++r) {
            const float* ar = act + (size_t)(r0 + r) * 64 + g * 8;
            float4 v0 = *(const float4*)(ar);
            float4 v1 = *(const float4*)(ar + 4);
            a[r][0] = v0.x; a[r][1] = v0.y; a[r][2] = v0.z; a[r][3] = v0.w;
            a[r][4] = v1.x; a[r][5] = v1.y; a[r][6] = v1.z; a[r][7] = v1.w;
        }
#pragma unroll
        for (int f = 0; f < 8; ++f) {
            const float4* m4 = (const float4*)(sMt + (g * 8 + f) * 20);
            float4 ma = m4[0], mb = m4[1], mc = m4[2], md = m4[3], me = m4[4];
#pragma unroll
            for (int r = 0; r < 4; ++r) {
                float av = a[r][f];
                zp[r][0] += av * ma.x; zp[r][1] += av * ma.y; zp[r][2] += av * ma.z; zp[r][3] += av * ma.w;
                zp[r][4] += av * mb.x; zp[r][5] += av * mb.y; zp[r][6] += av * mb.z; zp[r][7] += av * mb.w;
                zp[r][8] += av * mc.x; zp[r][9] += av * mc.y; zp[r][10] += av * mc.z; zp[r][11] += av * mc.w;
                zp[r][12] += av * md.x; zp[r][13] += av * md.y; zp[r][14] += av * md.z; zp[r][15] += av * md.w;
                zp[r][16] += av * me.x; zp[r][17] += av * me.y; zp[r][18] += av * me.z; zp[r][19] += av * me.w;
            }
        }
    }

    // coalesced col-major store: z[j][r0..r0+3]
#pragma unroll
    for (int j = 0; j < 20; ++j) {
        *(float4*)(zout + (size_t)j * B_N + r0) =
            make_float4(zp[0][j], zp[1][j], zp[2][j], zp[3][j]);
    }

    // BN2 stats
    float s_[20], q_[20];
#pragma unroll
    for (int j = 0; j < 20; ++j) {
        float s = zp[0][j] + zp[1][j] + zp[2][j] + zp[3][j];
        float q = zp[0][j]*zp[0][j] + zp[1][j]*zp[1][j] + zp[2][j]*zp[2][j] + zp[3][j]*zp[3][j];
        s_[j] = s; q_[j] = q;
    }
#pragma unroll
    for (int off = 32; off >= 1; off >>= 1) {
#pragma unroll
        for (int j = 0; j < 20; ++j) {
            s_[j] += __shfl_down(s_[j], off, 64);
            q_[j] += __shfl_down(q_[j], off, 64);
        }
    }
    const int wave = t >> 6, lane = t & 63;
    if (lane == 0) {
#pragma unroll
        for (int j = 0; j < 20; ++j) {
            sRed[wave][j] = s_[j];
            sRed[wave][20 + j] = q_[j];
        }
    }
    __syncthreads();
    if (t < 40) {
        float v = sRed[0][t] + sRed[1][t];
        atomicAdd(&stat2[(blockIdx.x & 63) * 40 + t], v);
    }
}

// ---------------- fallback pass 2 (mode 0/1): recompute RBF ----------------
__device__ __forceinline__ void zpre_row(
    const float* __restrict__ xr, const float4* __restrict__ sRbf,
    const float* __restrict__ sLin, const float* __restrict__ sMt,
    const float* __restrict__ sC, float zp[20])
{
#pragma unroll
    for (int j = 0; j < 20; ++j) zp[j] = sC[j];
#pragma unroll 1
    for (int g = 0; g < 8; ++g) {
        float4 v0 = *(const float4*)(xr + g * 8);
        float4 v1 = *(const float4*)(xr + g * 8 + 4);
        float xv[8] = {v0.x, v0.y, v0.z, v0.w, v1.x, v1.y, v1.z, v1.w};
        float act[8];
        float lin = sLin[g];
#pragma unroll
        for (int f = 0; f < 8; ++f) act[f] = lin * xv[f];
#pragma unroll 1
        for (int k = 0; k < 8; ++k) {
            float4 p = sRbf[g * 8 + k];
#pragma unroll
            for (int f = 0; f < 8; ++f) {
                float d = xv[f] - p.x;
                act[f] += p.y * __expf(d * d * p.z);
            }
        }
#pragma unroll 1
        for (int f = 0; f < 8; ++f) {
            float av = act[f];
            const float4* m4 = (const float4*)(sMt + (g * 8 + f) * 20);
            float4 ma = m4[0], mb = m4[1], mc = m4[2], md = m4[3], me = m4[4];
            zp[0] += av * ma.x; zp[1] += av * ma.y; zp[2] += av * ma.z; zp[3] += av * ma.w;
            zp[4] += av * mb.x; zp[5] += av * mb.y; zp[6] += av * mb.z; zp[7] += av * mb.w;
            zp[8] += av * mc.x; zp[9] += av * mc.y; zp[10] += av * mc.z; zp[11] += av * mc.w;
            zp[12] += av * md.x; zp[13] += av * md.y; zp[14] += av * md.z; zp[15] += av * md.w;
            zp[16] += av * me.x; zp[17] += av * me.y; zp[18] += av * me.z; zp[19] += av * me.w;
        }
    }
}

__device__ __forceinline__ void load_rbf_lds(
    const float* cen, const float* lw, const float* rw, const float* linw,
    const float* Mt, const float* Cc,
    float4* sRbf, float* sLin, float* sMt, float* sC, int t)
{
    if (t < 64) {
        float s = expf(lw[t]) + 1e-6f;
        sRbf[t] = make_float4(cen[t], rw[t], -0.5f / (s * s), 0.0f);
    }
    if (t < 8)  sLin[t] = linw[t];
    if (t < 20) sC[t] = Cc[t];
    for (int i = t; i < 1280; i += 256) sMt[i] = Mt[i];
}

__global__ __launch_bounds__(256) void k_zpre_stats(
    const float* __restrict__ x, const float* __restrict__ cen,
    const float* __restrict__ lw, const float* __restrict__ rw,
    const float* __restrict__ linw, const float* __restrict__ Mt,
    const float* __restrict__ Cc, float* __restrict__ zout,
    float* __restrict__ stat2, int store)
{
    __shared__ __align__(16) float4 sRbf[64];
    __shared__ float sLin[8], sC[20];
    __shared__ __align__(16) float sMt[1280];
    __shared__ float sRed[4][40];

    const int t = threadIdx.x;
    load_rbf_lds(cen, lw, rw, linw, Mt, Cc, sRbf, sLin, sMt, sC, t);
    __syncthreads();

    const int row = blockIdx.x * 256 + t;
    float zp[20];
    zpre_row(x + (size_t)row * 64, sRbf, sLin, sMt, sC, zp);
    if (store) {
#pragma unroll
        for (int j = 0; j < 20; ++j) zout[(size_t)j * B_N + row] = zp[j];
    }
    float s_[20], q_[20];
#pragma unroll
    for (int j = 0; j < 20; ++j) { s_[j] = zp[j]; q_[j] = zp[j] * zp[j]; }
#pragma unroll
    for (int off = 32; off >= 1; off >>= 1) {
#pragma unroll
        for (int j = 0; j < 20; ++j) {
            s_[j] += __shfl_down(s_[j], off, 64);
            q_[j] += __shfl_down(q_[j], off, 64);
        }
    }
    const int wave = t >> 6, lane = t & 63;
    if (lane == 0) {
#pragma unroll
        for (int j = 0; j < 20; ++j) { sRed[wave][j] = s_[j]; sRed[wave][20 + j] = q_[j]; }
    }
    __syncthreads();
    if (t < 40) {
        float v = sRed[0][t] + sRed[1][t] + sRed[2][t] + sRed[3][t];
        atomicAdd(&stat2[(blockIdx.x & 63) * 40 + t], v);
    }
}

// ---------------- pass 3 helpers ----------------
__device__ __forceinline__ float gelu_exact(float v) {
    return 0.5f * v * (1.0f + erff(v * 0.70710678118654752440f));
}

__device__ __forceinline__ void bn2_inline(
    const float* stat2, const float* g2, const float* b2,
    float* sT, float* sSc, float* sSh, int t)
{
    if (t < 40) {
        float s = 0.0f;
        for (int st = 0; st < 64; ++st) s += stat2[st * 40 + t];
        sT[t] = s;
    }
    __syncthreads();
    if (t < 20) {
        float mu = sT[t] * (1.0f / B_N);
        float var = sT[20 + t] * (1.0f / B_N) - mu * mu;
        float sc = g2[t] * rsqrtf(var + 1e-5f);
        sSc[t] = sc;
        sSh[t] = b2[t] - mu * sc;
    }
}

// ---------------- pass 3 (mode 1/2): 2 rows/thread from z ----------------
__global__ __launch_bounds__(256) void k_out2(
    const float* __restrict__ zin, const float* __restrict__ stat2,
    const float* __restrict__ g2, const float* __restrict__ b2,
    const float* __restrict__ nh, const float* __restrict__ fzc,
    const float* __restrict__ hW, const float* __restrict__ hb,
    float* __restrict__ out)
{
    __shared__ float sT[40], sSc[20], sSh[20], sHW[10];
    __shared__ __align__(16) float4 sFz[200];
    const int t = threadIdx.x;
    if (t < 10) sHW[t] = hW[t];
    for (int i = t; i < 200; i += 256)
        sFz[i] = make_float4(fzc[i], nh[i], nh[200 + i], 0.0f);
    bn2_inline(stat2, g2, b2, sT, sSc, sSh, t);
    __syncthreads();

    const int r0 = (blockIdx.x * 256 + t) * 2;
    float z0[20], z1[20];
#pragma unroll
    for (int j = 0; j < 20; ++j) {
        float2 v = *(const float2*)(zin + (size_t)j * B_N + r0);
        z0[j] = gelu_exact(sSc[j] * v.x + sSh[j]);
        z1[j] = gelu_exact(sSc[j] * v.y + sSh[j]);
    }
    const float hbv = hb[0];
    float acc0 = hbv, acc1 = hbv;
#pragma unroll 1
    for (int r = 0; r < 10; ++r) {
        float u0 = 0.0f, l0 = 0.0f, u1 = 0.0f, l1 = 0.0f;
#pragma unroll
        for (int j = 0; j < 20; ++j) {
            float4 p = sFz[r * 20 + j];
            float d0 = z0[j] - p.x, d1 = z1[j] - p.x;
            float dd0 = d0 * d0, dd1 = d1 * d1;
            u0 += __expf(dd0 * p.y); l0 += __expf(dd0 * p.z);
            u1 += __expf(dd1 * p.y); l1 += __expf(dd1 * p.z);
        }
        float w = sHW[r] * 0.025f;
        acc0 += w * (u0 + l0);
        acc1 += w * (u1 + l1);
    }
    *(float2*)(out + r0) = make_float2(acc0, acc1);
}

// ---------------- pass 3 (mode 0): recompute everything ----------------
__global__ __launch_bounds__(256) void k_out_rec(
    const float* __restrict__ x, const float* __restrict__ cen,
    const float* __restrict__ lw, const float* __restrict__ rw,
    const float* __restrict__ linw, const float* __restrict__ Mt,
    const float* __restrict__ Cc, const float* __restrict__ stat2,
    const float* __restrict__ g2, const float* __restrict__ b2,
    const float* __restrict__ nh, const float* __restrict__ fzc,
    const float* __restrict__ hW, const float* __restrict__ hb,
    float* __restrict__ out)
{
    __shared__ __align__(16) float4 sRbf[64];
    __shared__ float sLin[8], sC[20];
    __shared__ __align__(16) float sMt[1280];
    __shared__ float sT[40], sSc[20], sSh[20], sHW[10];
    __shared__ __align__(16) float4 sFz[200];

    const int t = threadIdx.x;
    load_rbf_lds(cen, lw, rw, linw, Mt, Cc, sRbf, sLin, sMt, sC, t);
    if (t < 10) sHW[t] = hW[t];
    for (int i = t; i < 200; i += 256)
        sFz[i] = make_float4(fzc[i], nh[i], nh[200 + i], 0.0f);
    bn2_inline(stat2, g2, b2, sT, sSc, sSh, t);
    __syncthreads();

    const int row = blockIdx.x * 256 + t;
    float zp[20];
    zpre_row(x + (size_t)row * 64, sRbf, sLin, sMt, sC, zp);
    float z[20];
#pragma unroll
    for (int j = 0; j < 20; ++j)
        z[j] = gelu_exact(sSc[j] * zp[j] + sSh[j]);
    float acc = hb[0];
#pragma unroll 1
    for (int r = 0; r < 10; ++r) {
        float u = 0.0f, l = 0.0f;
#pragma unroll
        for (int j = 0; j < 20; ++j) {
            float4 p = sFz[r * 20 + j];
            float d = z[j] - p.x;
            float dd = d * d;
            u += __expf(dd * p.y);
            l += __expf(dd * p.z);
        }
        acc += sHW[r] * 0.025f * (u + l);
    }
    out[row] = acc;
}

// ---------------- launcher ----------------
extern "C" void kernel_launch(void* const* d_in, const int* in_sizes, int n_in,
                              void* d_out, int out_size, void* d_ws, size_t ws_size,
                              hipStream_t stream) {
    const float* x    = (const float*)d_in[0];
    const float* cen  = (const float*)d_in[1];
    const float* lw   = (const float*)d_in[2];
    const float* rw   = (const float*)d_in[3];
    const float* linw = (const float*)d_in[4];
    const float* Wp   = (const float*)d_in[5];
    const float* pb   = (const float*)d_in[6];
    const float* g1   = (const float*)d_in[7];
    const float* b1   = (const float*)d_in[8];
    const float* fpW  = (const float*)d_in[9];
    const float* fpb  = (const float*)d_in[10];
    const float* g2   = (const float*)d_in[11];
    const float* b2   = (const float*)d_in[12];
    const float* fzc  = (const float*)d_in[13];
    const float* lsu  = (const float*)d_in[14];
    const float* lsl  = (const float*)d_in[15];
    const float* hW   = (const float*)d_in[16];
    const float* hb   = (const float*)d_in[17];

    float* ws    = (float*)d_ws;
    float* stat1 = ws + WS_STAT1;
    float* Mt    = ws + WS_MT;
    float* Cc    = ws + WS_C;
    float* stat2 = ws + WS_STAT2;
    float* nh    = ws + WS_NH;
    float* actb  = ws + WS_ACT;
    float* outp  = (float*)d_out;

    const size_t needFull = (WS_ZFULL + (size_t)20 * B_N) * sizeof(float);
    const size_t needZ    = ((size_t)WS_Z2 + (size_t)20 * B_N) * sizeof(float);
    int mode = (ws_size >= needFull) ? 2 : (ws_size >= needZ ? 1 : 0);
    float* zbuf = (mode == 2) ? (ws + WS_ZFULL) : (ws + WS_Z2);

    hipMemsetAsync(stat1, 0, (size_t)ST1_SZ * sizeof(float), stream);
    k_act_moments<<<1024, 256, 0, stream>>>(x, cen, lw, rw, linw, actb, stat1,
                                            mode == 2 ? 1 : 0);
    k_build<<<1, 256, 0, stream>>>(stat1, fpW, fpb, g1, b1, Wp, pb, lsu, lsl,
                                   Mt, Cc, nh, stat2);
    if (mode == 2) {
        k_z_from_act<<<256, 128, 0, stream>>>(actb, Mt, Cc, zbuf, stat2);
        k_out2<<<256, 256, 0, stream>>>(zbuf, stat2, g2, b2, nh, fzc, hW, hb, outp);
    } else if (mode == 1) {
        k_zpre_stats<<<512, 256, 0, stream>>>(x, cen, lw, rw, linw, Mt, Cc,
                                              zbuf, stat2, 1);
        k_out2<<<256, 256, 0, stream>>>(zbuf, stat2, g2, b2, nh, fzc, hW, hb, outp);
    } else {
        k_zpre_stats<<<512, 256, 0, stream>>>(x, cen, lw, rw, linw, Mt, Cc,
                                              nullptr, stat2, 0);
        k_out_rec<<<512, 256, 0, stream>>>(x, cen, lw, rw, linw, Mt, Cc,
                                           stat2, g2, b2, nh, fzc, hW, hb, outp);
    }
}